// Round 6
// baseline (454.396 us; speedup 1.0000x reference)
//
#include <hip/hip_runtime.h>
#include <math.h>

#define N_NODES 50000
#define N_EDGES 800000
#define H 128
#define EIN 257
#define EPB 64   // edges per block
#define NPB 64   // nodes per block

typedef short bf16x8 __attribute__((ext_vector_type(8)));
typedef short bf16x4 __attribute__((ext_vector_type(4)));
typedef short bf16x2 __attribute__((ext_vector_type(2)));
typedef float f32x4 __attribute__((ext_vector_type(4)));

// round-to-nearest-even f32 -> bf16 (one-time prep conversions)
static __device__ __forceinline__ short f2bf(float x) {
    unsigned u = __builtin_bit_cast(unsigned, x);
    unsigned r = (u + 0x7FFFu + ((u >> 16) & 1u)) >> 16;
    return (short)r;
}

// cheap round-half-up f32 -> bf16 (2 VALU insts)
static __device__ __forceinline__ short f2bfr(float x) {
    return (short)((__builtin_bit_cast(unsigned, x) + 0x8000u) >> 16);
}

// fast silu
static __device__ __forceinline__ float silu(float x) {
#if __has_builtin(__builtin_amdgcn_rcpf)
    return x * __builtin_amdgcn_rcpf(1.0f + __expf(-x));
#else
    return x / (1.0f + __expf(-x));
#endif
}

// packed bf16 atomic add
static __device__ __forceinline__ void pk_agg_add(unsigned* addr, unsigned val) {
#if __has_builtin(__builtin_amdgcn_global_atomic_fadd_v2bf16)
    bf16x2 v = __builtin_bit_cast(bf16x2, val);
    (void)__builtin_amdgcn_global_atomic_fadd_v2bf16(
        (__attribute__((address_space(1))) bf16x2*)(unsigned long long)addr, v);
#else
    asm volatile("global_atomic_pk_add_bf16 %0, %1, off"
                 :: "v"(addr), "v"(val) : "memory");
#endif
}

// agg column permutation: stored bf16 index s -> logical col.
// dword d = w*16+l15 holds cols (32w+l15, 32w+16+l15). Baked into Wn1b.
static __device__ __forceinline__ int agg_colmap(int s) {
    return 32 * (s >> 5) + 16 * (s & 1) + ((s >> 1) & 15);
}

// ---- prep: h->bf16, weights->bf16 (padded), Wfuse=Wc1@We2, bc1f, agg zero, pos copy ----
#define P_W1  (128*264)
#define P_W2  (128*128)
#define NH4   (N_NODES * H / 4)          // 1,600,000
#define N_WF  (128*128)                  // Wfuse entries
#define AGG16 (N_NODES * H * 2 / 16)     // 800,000
#define POS4  ((N_NODES * 3 + 3) / 4)    // 37,500

__global__ __launch_bounds__(256) void prep_all(
    const float* __restrict__ hf,
    const float* __restrict__ We1, const float* __restrict__ We2,
    const float* __restrict__ Wc1, const float* __restrict__ Wn1,
    const float* __restrict__ Wn2,
    const float* __restrict__ bc1, const float* __restrict__ be2,
    short* __restrict__ hbf,
    short* __restrict__ W1b, short* __restrict__ W2b,
    short* __restrict__ Wn1b, short* __restrict__ Wn2b,
    short* __restrict__ Wfb, float* __restrict__ bc1f,
    uint4* __restrict__ aggz, int aggz_n,
    float4* __restrict__ pos_dst, const float4* __restrict__ pos_src)
{
    int i = blockIdx.x * 256 + threadIdx.x;
    if (i < NH4) {
        float4 v = ((const float4*)hf)[i];
        bf16x4 s4 = { f2bf(v.x), f2bf(v.y), f2bf(v.z), f2bf(v.w) };
        *(bf16x4*)&hbf[i * 4] = s4;
        return;
    }
    i -= NH4;
    if (i < P_W1) {                       // W1b [128][264]
        int j = i / 264, k = i % 264;
        W1b[i] = (k < EIN) ? f2bf(We1[j * EIN + k]) : (short)0;
        return;
    }
    i -= P_W1;
    if (i < P_W2) { W2b[i] = f2bf(We2[i]); return; }
    i -= P_W2;
    if (i < P_W1) {                       // Wn1b [128][264], k>=128 permuted to agg order
        int j = i / 264, k = i % 264;
        short v = 0;
        if (k < 128)      v = f2bf(Wn1[j * 256 + k]);
        else if (k < 256) v = f2bf(Wn1[j * 256 + 128 + agg_colmap(k - 128)]);
        Wn1b[i] = v;
        return;
    }
    i -= P_W1;
    if (i < P_W2) { Wn2b[i] = f2bf(Wn2[i]); return; }
    i -= P_W2;
    if (i < N_WF) {                       // Wfuse[j][k] = sum_i Wc1[j][i]*We2[i][k]
        int j = i >> 7, k = i & 127;
        float a = 0.0f;
        #pragma unroll 8
        for (int t = 0; t < 128; ++t)
            a += Wc1[j * 128 + t] * We2[t * 128 + k];
        Wfb[i] = f2bf(a);
        return;
    }
    i -= N_WF;
    if (i < 128) {                        // bc1f[j] = bc1[j] + sum_i Wc1[j][i]*be2[i]
        float a = bc1[i];
        #pragma unroll 8
        for (int t = 0; t < 128; ++t)
            a += Wc1[i * 128 + t] * be2[t];
        bc1f[i] = a;
        return;
    }
    i -= 128;
    if (i < aggz_n) { aggz[i] = uint4{0u, 0u, 0u, 0u}; return; }
    i -= aggz_n;
    if (i < POS4) pos_dst[i] = pos_src[i];
}

// ---- edge kernel: 64 edges / block, 256 threads (4 waves) ----
// m never materialized: GEMM3 fused as t @ (Wc1@We2)^T; agg atomics fire
// straight from GEMM2 accumulators in permuted-pair order.
template<bool AGGBF16>
__global__ __launch_bounds__(256, 4) void edge_kernel(
    const short* __restrict__ hbf, const float* __restrict__ pos,
    const int* __restrict__ eidx,
    const float* __restrict__ We1f, const float* __restrict__ be1,
    const float* __restrict__ be2, const float* __restrict__ bc1f,
    const float* __restrict__ wc2f, const float* __restrict__ bc2,
    const short* __restrict__ W1b, const short* __restrict__ W2b,
    const short* __restrict__ Wfb,
    unsigned* __restrict__ aggb,   // bf16 agg (permuted cols), 64 dwords/row
    float* __restrict__ aggf,      // f32 agg (fallback, permuted cols)
    float* __restrict__ pos_out)
{
    __shared__ union {
        short ein[EPB][264];   // 33792 B (phase A; dead after GEMM1 reads)
        short t[EPB][136];     // 17408 B (phase B)
    } s_u;
    __shared__ float s_rn[EPB];
    __shared__ float s_unit[EPB][3];
    __shared__ int   s_row[EPB];
    __shared__ float s_dot[EPB];

    const int tid = threadIdx.x;
    const int eb  = blockIdx.x * EPB;

    if (tid < EPB) {
        int ge = eb + tid;
        int r = eidx[ge];
        int c = eidx[N_EDGES + ge];
        s_row[tid] = r;
        float dx = pos[r*3+0] - pos[c*3+0];
        float dy = pos[r*3+1] - pos[c*3+1];
        float dz = pos[r*3+2] - pos[c*3+2];
        float nrm = sqrtf(dx*dx + dy*dy + dz*dz);
        float rn  = fmaxf(nrm, 1e-8f);
        s_rn[tid] = rn;
        s_unit[tid][0] = dx / rn;
        s_unit[tid][1] = dy / rn;
        s_unit[tid][2] = dz / rn;
        s_dot[tid] = 0.0f;
    }

    // gather hbf[row]|hbf[col] -> s_ein: pure bf16 16B moves.
    {
        const int rlane = tid & 15;
        const int row0  = tid >> 4;      // 0..15
        int idxs[8];
        #pragma unroll
        for (int it = 0; it < 8; ++it) {
            int rr = row0 + it * 16;     // 0..127
            int e  = rr & 63, sg = rr >> 6;
            idxs[it] = eidx[(sg ? N_EDGES : 0) + eb + e];
        }
        #pragma unroll
        for (int it = 0; it < 8; ++it) {
            int rr = row0 + it * 16;
            int e  = rr & 63, sg = rr >> 6;
            bf16x8 v = *(const bf16x8*)&hbf[(size_t)idxs[it] * H + rlane * 8];
            *(bf16x8*)&s_u.ein[e][sg * 128 + rlane * 8] = v;
        }
    }
    __syncthreads();   // barrier 1: ein ready

    const int lane = tid & 63;
    const int q    = lane >> 4;
    const int l15  = lane & 15;
    const int n0   = (tid >> 6) * 32;
    const int w    = tid >> 6;

    // ---------------- GEMM1: [64x257] @ We1^T ----------------
    f32x4 acc[4][2] = {};
    #pragma unroll
    for (int ks = 0; ks < 8; ++ks) {
        int k0 = ks * 32 + q * 8;
        bf16x8 a0 = *(const bf16x8*)&s_u.ein[l15][k0];
        bf16x8 a1 = *(const bf16x8*)&s_u.ein[16 + l15][k0];
        bf16x8 a2 = *(const bf16x8*)&s_u.ein[32 + l15][k0];
        bf16x8 a3 = *(const bf16x8*)&s_u.ein[48 + l15][k0];
        bf16x8 b0 = *(const bf16x8*)&W1b[(n0 + l15) * 264 + k0];
        bf16x8 b1 = *(const bf16x8*)&W1b[(n0 + 16 + l15) * 264 + k0];
        acc[0][0] = __builtin_amdgcn_mfma_f32_16x16x32_bf16(a0, b0, acc[0][0], 0, 0, 0);
        acc[0][1] = __builtin_amdgcn_mfma_f32_16x16x32_bf16(a0, b1, acc[0][1], 0, 0, 0);
        acc[1][0] = __builtin_amdgcn_mfma_f32_16x16x32_bf16(a1, b0, acc[1][0], 0, 0, 0);
        acc[1][1] = __builtin_amdgcn_mfma_f32_16x16x32_bf16(a1, b1, acc[1][1], 0, 0, 0);
        acc[2][0] = __builtin_amdgcn_mfma_f32_16x16x32_bf16(a2, b0, acc[2][0], 0, 0, 0);
        acc[2][1] = __builtin_amdgcn_mfma_f32_16x16x32_bf16(a2, b1, acc[2][1], 0, 0, 0);
        acc[3][0] = __builtin_amdgcn_mfma_f32_16x16x32_bf16(a3, b0, acc[3][0], 0, 0, 0);
        acc[3][1] = __builtin_amdgcn_mfma_f32_16x16x32_bf16(a3, b1, acc[3][1], 0, 0, 0);
    }
    // epilogue 1 into registers (ein live until barrier 2)
    short tv[2][4][4];
    #pragma unroll
    for (int ct = 0; ct < 2; ++ct) {
        int col = n0 + ct * 16 + l15;
        float w256 = We1f[col * EIN + 256];   // rank-1 fixup for odd K
        float bias = be1[col];
        #pragma unroll
        for (int rt = 0; rt < 4; ++rt) {
            #pragma unroll
            for (int r = 0; r < 4; ++r) {
                int row = rt * 16 + q * 4 + r;
                tv[ct][rt][r] = f2bfr(silu(acc[rt][ct][r] + s_rn[row] * w256 + bias));
            }
        }
    }
    __syncthreads();   // barrier 2: ein reads done -> t may overlay
    #pragma unroll
    for (int ct = 0; ct < 2; ++ct) {
        int col = n0 + ct * 16 + l15;
        #pragma unroll
        for (int rt = 0; rt < 4; ++rt)
            #pragma unroll
            for (int r = 0; r < 4; ++r)
                s_u.t[rt * 16 + q * 4 + r][col] = tv[ct][rt][r];
    }
    __syncthreads();   // barrier 3: t ready

    // -------- merged GEMM2 (t @ We2^T) + GEMM3 (t @ Wfuse^T), shared A --------
    f32x4 acc2[4][2] = {};
    f32x4 acc3[4][2] = {};
    #pragma unroll
    for (int ks = 0; ks < 4; ++ks) {
        int k0 = ks * 32 + q * 8;
        bf16x8 a0 = *(const bf16x8*)&s_u.t[l15][k0];
        bf16x8 a1 = *(const bf16x8*)&s_u.t[16 + l15][k0];
        bf16x8 a2 = *(const bf16x8*)&s_u.t[32 + l15][k0];
        bf16x8 a3 = *(const bf16x8*)&s_u.t[48 + l15][k0];
        {
            bf16x8 b0 = *(const bf16x8*)&W2b[(n0 + l15) * 128 + k0];
            bf16x8 b1 = *(const bf16x8*)&W2b[(n0 + 16 + l15) * 128 + k0];
            acc2[0][0] = __builtin_amdgcn_mfma_f32_16x16x32_bf16(a0, b0, acc2[0][0], 0, 0, 0);
            acc2[0][1] = __builtin_amdgcn_mfma_f32_16x16x32_bf16(a0, b1, acc2[0][1], 0, 0, 0);
            acc2[1][0] = __builtin_amdgcn_mfma_f32_16x16x32_bf16(a1, b0, acc2[1][0], 0, 0, 0);
            acc2[1][1] = __builtin_amdgcn_mfma_f32_16x16x32_bf16(a1, b1, acc2[1][1], 0, 0, 0);
            acc2[2][0] = __builtin_amdgcn_mfma_f32_16x16x32_bf16(a2, b0, acc2[2][0], 0, 0, 0);
            acc2[2][1] = __builtin_amdgcn_mfma_f32_16x16x32_bf16(a2, b1, acc2[2][1], 0, 0, 0);
            acc2[3][0] = __builtin_amdgcn_mfma_f32_16x16x32_bf16(a3, b0, acc2[3][0], 0, 0, 0);
            acc2[3][1] = __builtin_amdgcn_mfma_f32_16x16x32_bf16(a3, b1, acc2[3][1], 0, 0, 0);
        }
        {
            bf16x8 c0 = *(const bf16x8*)&Wfb[(n0 + l15) * 128 + k0];
            bf16x8 c1 = *(const bf16x8*)&Wfb[(n0 + 16 + l15) * 128 + k0];
            acc3[0][0] = __builtin_amdgcn_mfma_f32_16x16x32_bf16(a0, c0, acc3[0][0], 0, 0, 0);
            acc3[0][1] = __builtin_amdgcn_mfma_f32_16x16x32_bf16(a0, c1, acc3[0][1], 0, 0, 0);
            acc3[1][0] = __builtin_amdgcn_mfma_f32_16x16x32_bf16(a1, c0, acc3[1][0], 0, 0, 0);
            acc3[1][1] = __builtin_amdgcn_mfma_f32_16x16x32_bf16(a1, c1, acc3[1][1], 0, 0, 0);
            acc3[2][0] = __builtin_amdgcn_mfma_f32_16x16x32_bf16(a2, c0, acc3[2][0], 0, 0, 0);
            acc3[2][1] = __builtin_amdgcn_mfma_f32_16x16x32_bf16(a2, c1, acc3[2][1], 0, 0, 0);
            acc3[3][0] = __builtin_amdgcn_mfma_f32_16x16x32_bf16(a3, c0, acc3[3][0], 0, 0, 0);
            acc3[3][1] = __builtin_amdgcn_mfma_f32_16x16x32_bf16(a3, c1, acc3[3][1], 0, 0, 0);
        }
    }

    // ---- agg atomics straight from acc2 (permuted pair order), fire-and-forget ----
    {
        float b2lo = be2[n0 + l15];
        float b2hi = be2[n0 + 16 + l15];
        #pragma unroll
        for (int rt = 0; rt < 4; ++rt) {
            #pragma unroll
            for (int r = 0; r < 4; ++r) {
                int row = rt * 16 + q * 4 + r;
                float lo = acc2[rt][0][r] + b2lo;
                float hi = acc2[rt][1][r] + b2hi;
                if constexpr (AGGBF16) {
                    unsigned d = (unsigned)(unsigned short)f2bfr(lo)
                               | ((unsigned)(unsigned short)f2bfr(hi) << 16);
                    pk_agg_add(&aggb[(size_t)s_row[row] * 64 + w * 16 + l15], d);
                } else {
                    float* dst = &aggf[(size_t)s_row[row] * H + 2 * (w * 16 + l15)];
                    atomicAdd(dst,     lo);
                    atomicAdd(dst + 1, hi);
                }
            }
        }
    }

    // ---- coord path from acc3 ----
    float p[4][4] = {};
    #pragma unroll
    for (int ct = 0; ct < 2; ++ct) {
        int col = n0 + ct * 16 + l15;
        float bias = bc1f[col];
        float w2 = wc2f[col];
        #pragma unroll
        for (int rt = 0; rt < 4; ++rt) {
            #pragma unroll
            for (int r = 0; r < 4; ++r)
                p[rt][r] += silu(acc3[rt][ct][r] + bias) * w2;
        }
    }
    #pragma unroll
    for (int rt = 0; rt < 4; ++rt) {
        #pragma unroll
        for (int r = 0; r < 4; ++r) {
            float v = p[rt][r];
            v += __shfl_xor(v, 1);
            v += __shfl_xor(v, 2);
            v += __shfl_xor(v, 4);
            v += __shfl_xor(v, 8);
            if (l15 == 0) atomicAdd(&s_dot[rt * 16 + q * 4 + r], v);
        }
    }
    __syncthreads();   // barrier 4 (last)

    if (tid < EPB) {
        float s = tanhf(s_dot[tid] + bc2[0]) * 0.1f;
        int r = s_row[tid];
        atomicAdd(&pos_out[r * 3 + 0], s * s_unit[tid][0]);
        atomicAdd(&pos_out[r * 3 + 1], s * s_unit[tid][1]);
        atomicAdd(&pos_out[r * 3 + 2], s * s_unit[tid][2]);
    }
}

// ---- node kernel: 64 nodes / block, union overlay (agg cols pre-permuted in Wn1b) ----
template<bool AGGBF16>
__global__ __launch_bounds__(256, 4) void node_kernel(
    const float* __restrict__ h, const short* __restrict__ hbf,
    const unsigned short* __restrict__ aggb, const float* __restrict__ aggf,
    const float* __restrict__ bn1, const float* __restrict__ bn2,
    const short* __restrict__ Wn1b, const short* __restrict__ Wn2b,
    float* __restrict__ hout)
{
    __shared__ union {
        short a[NPB][264];
        short t[NPB][136];
    } s_u;

    const int tid = threadIdx.x;
    const int nb  = blockIdx.x * NPB;

    {
        const int rlane = tid & 15;
        const int row0  = tid >> 4;
        #pragma unroll
        for (int it = 0; it < 8; ++it) {
            int rr = row0 + it * 16;     // 0..127
            int e  = rr & 63, sg = rr >> 6;
            int node = nb + e;
            if (node >= N_NODES) node = N_NODES - 1;
            bf16x8 v;
            if (sg == 0) {
                v = *(const bf16x8*)&hbf[(size_t)node * H + rlane * 8];
            } else if constexpr (AGGBF16) {
                v = *(const bf16x8*)&aggb[(size_t)node * H + rlane * 8];
            } else {
                const float* src = &aggf[(size_t)node * H + rlane * 8];
                bf16x8 t;
                #pragma unroll
                for (int j = 0; j < 8; ++j) t[j] = f2bfr(src[j]);
                v = t;
            }
            *(bf16x8*)&s_u.a[e][sg * 128 + rlane * 8] = v;
        }
    }
    __syncthreads();

    const int lane = tid & 63;
    const int q    = lane >> 4;
    const int l15  = lane & 15;
    const int n0   = (tid >> 6) * 32;

    f32x4 acc[4][2] = {};
    #pragma unroll
    for (int ks = 0; ks < 8; ++ks) {
        int k0 = ks * 32 + q * 8;
        bf16x8 a0 = *(const bf16x8*)&s_u.a[l15][k0];
        bf16x8 a1 = *(const bf16x8*)&s_u.a[16 + l15][k0];
        bf16x8 a2 = *(const bf16x8*)&s_u.a[32 + l15][k0];
        bf16x8 a3 = *(const bf16x8*)&s_u.a[48 + l15][k0];
        bf16x8 b0 = *(const bf16x8*)&Wn1b[(n0 + l15) * 264 + k0];
        bf16x8 b1 = *(const bf16x8*)&Wn1b[(n0 + 16 + l15) * 264 + k0];
        acc[0][0] = __builtin_amdgcn_mfma_f32_16x16x32_bf16(a0, b0, acc[0][0], 0, 0, 0);
        acc[0][1] = __builtin_amdgcn_mfma_f32_16x16x32_bf16(a0, b1, acc[0][1], 0, 0, 0);
        acc[1][0] = __builtin_amdgcn_mfma_f32_16x16x32_bf16(a1, b0, acc[1][0], 0, 0, 0);
        acc[1][1] = __builtin_amdgcn_mfma_f32_16x16x32_bf16(a1, b1, acc[1][1], 0, 0, 0);
        acc[2][0] = __builtin_amdgcn_mfma_f32_16x16x32_bf16(a2, b0, acc[2][0], 0, 0, 0);
        acc[2][1] = __builtin_amdgcn_mfma_f32_16x16x32_bf16(a2, b1, acc[2][1], 0, 0, 0);
        acc[3][0] = __builtin_amdgcn_mfma_f32_16x16x32_bf16(a3, b0, acc[3][0], 0, 0, 0);
        acc[3][1] = __builtin_amdgcn_mfma_f32_16x16x32_bf16(a3, b1, acc[3][1], 0, 0, 0);
    }
    short tv[2][4][4];
    #pragma unroll
    for (int ct = 0; ct < 2; ++ct) {
        int col = n0 + ct * 16 + l15;
        float bias = bn1[col];
        #pragma unroll
        for (int rt = 0; rt < 4; ++rt)
            #pragma unroll
            for (int r = 0; r < 4; ++r)
                tv[ct][rt][r] = f2bfr(silu(acc[rt][ct][r] + bias));
    }
    __syncthreads();   // a reads done -> t may overlay
    #pragma unroll
    for (int ct = 0; ct < 2; ++ct) {
        int col = n0 + ct * 16 + l15;
        #pragma unroll
        for (int rt = 0; rt < 4; ++rt)
            #pragma unroll
            for (int r = 0; r < 4; ++r)
                s_u.t[rt * 16 + q * 4 + r][col] = tv[ct][rt][r];
    }
    __syncthreads();

    f32x4 acc2[4][2] = {};
    #pragma unroll
    for (int ks = 0; ks < 4; ++ks) {
        int k0 = ks * 32 + q * 8;
        bf16x8 a0 = *(const bf16x8*)&s_u.t[l15][k0];
        bf16x8 a1 = *(const bf16x8*)&s_u.t[16 + l15][k0];
        bf16x8 a2 = *(const bf16x8*)&s_u.t[32 + l15][k0];
        bf16x8 a3 = *(const bf16x8*)&s_u.t[48 + l15][k0];
        bf16x8 b0 = *(const bf16x8*)&Wn2b[(n0 + l15) * 128 + k0];
        bf16x8 b1 = *(const bf16x8*)&Wn2b[(n0 + 16 + l15) * 128 + k0];
        acc2[0][0] = __builtin_amdgcn_mfma_f32_16x16x32_bf16(a0, b0, acc2[0][0], 0, 0, 0);
        acc2[0][1] = __builtin_amdgcn_mfma_f32_16x16x32_bf16(a0, b1, acc2[0][1], 0, 0, 0);
        acc2[1][0] = __builtin_amdgcn_mfma_f32_16x16x32_bf16(a1, b0, acc2[1][0], 0, 0, 0);
        acc2[1][1] = __builtin_amdgcn_mfma_f32_16x16x32_bf16(a1, b1, acc2[1][1], 0, 0, 0);
        acc2[2][0] = __builtin_amdgcn_mfma_f32_16x16x32_bf16(a2, b0, acc2[2][0], 0, 0, 0);
        acc2[2][1] = __builtin_amdgcn_mfma_f32_16x16x32_bf16(a2, b1, acc2[2][1], 0, 0, 0);
        acc2[3][0] = __builtin_amdgcn_mfma_f32_16x16x32_bf16(a3, b0, acc2[3][0], 0, 0, 0);
        acc2[3][1] = __builtin_amdgcn_mfma_f32_16x16x32_bf16(a3, b1, acc2[3][1], 0, 0, 0);
    }
    #pragma unroll
    for (int ct = 0; ct < 2; ++ct) {
        int col = n0 + ct * 16 + l15;
        float bias = bn2[col];
        #pragma unroll
        for (int rt = 0; rt < 4; ++rt) {
            #pragma unroll
            for (int r = 0; r < 4; ++r) {
                int row = rt * 16 + q * 4 + r;
                int nrow = nb + row;
                if (nrow < N_NODES) {
                    float v = acc2[rt][ct][r] + bias + h[(size_t)nrow * H + col];
                    hout[(size_t)nrow * H + col] = v;
                }
            }
        }
    }
}

extern "C" void kernel_launch(void* const* d_in, const int* in_sizes, int n_in,
                              void* d_out, int out_size, void* d_ws, size_t ws_size,
                              hipStream_t stream) {
    const float* h   = (const float*)d_in[0];
    const float* pos = (const float*)d_in[1];
    const int*  eidx = (const int*)d_in[2];
    const float* We1 = (const float*)d_in[3];
    const float* be1 = (const float*)d_in[4];
    const float* We2 = (const float*)d_in[5];
    const float* be2 = (const float*)d_in[6];
    const float* Wn1 = (const float*)d_in[7];
    const float* bn1 = (const float*)d_in[8];
    const float* Wn2 = (const float*)d_in[9];
    const float* bn2 = (const float*)d_in[10];
    const float* Wc1 = (const float*)d_in[11];
    const float* bc1 = (const float*)d_in[12];
    const float* Wc2 = (const float*)d_in[13];
    const float* bc2 = (const float*)d_in[14];

    float* out_h   = (float*)d_out;
    float* out_pos = out_h + (size_t)N_NODES * H;

    char* ws = (char*)d_ws;
    short* W1b  = (short*)(ws);
    short* W2b  = (short*)(ws + 2 * (size_t)P_W1);
    short* Wfb  = (short*)(ws + 2 * (size_t)(P_W1 + P_W2));
    short* Wn1b = (short*)(ws + 2 * (size_t)(P_W1 + 2 * P_W2));
    short* Wn2b = (short*)(ws + 2 * (size_t)(2 * P_W1 + 2 * P_W2));
    const size_t WSW = 2 * (size_t)(2 * P_W1 + 3 * P_W2);   // 233472 B
    float* bc1f = (float*)(ws + WSW);                        // 512 B slot
    const size_t HOFF = WSW + 512;
    const size_t HBF = (size_t)N_NODES * H * 2;             // 12.8 MB
    const size_t AGG = (size_t)N_NODES * H * 2;             // 12.8 MB
    short* hbf = (short*)(ws + HOFF);
    const bool use_bf16 = (ws_size >= HOFF + HBF + AGG);

    if (use_bf16) {
        unsigned* aggb = (unsigned*)(ws + HOFF + HBF);
        const int prep_n = NH4 + 2 * P_W1 + 2 * P_W2 + N_WF + 128 + AGG16 + POS4;
        prep_all<<<(prep_n + 255) / 256, 256, 0, stream>>>(
            h, We1, We2, Wc1, Wn1, Wn2, bc1, be2,
            hbf, W1b, W2b, Wn1b, Wn2b, Wfb, bc1f,
            (uint4*)aggb, AGG16, (float4*)out_pos, (const float4*)pos);
        edge_kernel<true><<<N_EDGES / EPB, 256, 0, stream>>>(
            hbf, pos, eidx, We1, be1, be2, bc1f, Wc2, bc2,
            W1b, W2b, Wfb, aggb, nullptr, out_pos);
        node_kernel<true><<<(N_NODES + NPB - 1) / NPB, 256, 0, stream>>>(
            h, hbf, (const unsigned short*)aggb, nullptr,
            bn1, bn2, Wn1b, Wn2b, out_h);
    } else {
        // fallback: f32 agg (permuted col order) in d_out h region
        const int prep_n = NH4 + 2 * P_W1 + 2 * P_W2 + N_WF + 128 + POS4;
        prep_all<<<(prep_n + 255) / 256, 256, 0, stream>>>(
            h, We1, We2, Wc1, Wn1, Wn2, bc1, be2,
            hbf, W1b, W2b, Wn1b, Wn2b, Wfb, bc1f,
            nullptr, 0, (float4*)out_pos, (const float4*)pos);
        hipMemsetAsync(out_h, 0, (size_t)N_NODES * H * sizeof(float), stream);
        edge_kernel<false><<<N_EDGES / EPB, 256, 0, stream>>>(
            hbf, pos, eidx, We1, be1, be2, bc1f, Wc2, bc2,
            W1b, W2b, Wfb, nullptr, out_h, out_pos);
        node_kernel<false><<<(N_NODES + NPB - 1) / NPB, 256, 0, stream>>>(
            h, hbf, nullptr, out_h, bn1, bn2, Wn1b, Wn2b, out_h);
    }
}